// Round 16
// baseline (11022.836 us; speedup 1.0000x reference)
//
#include <hip/hip_runtime.h>
#include <hip/hip_bf16.h>
#include <cstdint>

#define NEGV  (-1e9f)

// ---------------- threefry2x32 (exact JAX semantics) ----------------
__device__ __forceinline__ void threefry2x32(uint32_t k0, uint32_t k1,
                                             uint32_t x0, uint32_t x1,
                                             uint32_t& o0, uint32_t& o1) {
  uint32_t ks0 = k0, ks1 = k1, ks2 = k0 ^ k1 ^ 0x1BD11BDAu;
  x0 += ks0; x1 += ks1;
#define TF_RND(r) { x0 += x1; x1 = (x1 << (r)) | (x1 >> (32 - (r))); x1 ^= x0; }
  TF_RND(13) TF_RND(15) TF_RND(26) TF_RND(6)
  x0 += ks1; x1 += ks2 + 1u;
  TF_RND(17) TF_RND(29) TF_RND(16) TF_RND(24)
  x0 += ks2; x1 += ks0 + 2u;
  TF_RND(13) TF_RND(15) TF_RND(26) TF_RND(6)
  x0 += ks0; x1 += ks1 + 3u;
  TF_RND(17) TF_RND(29) TF_RND(16) TF_RND(24)
  x0 += ks1; x1 += ks2 + 4u;
  TF_RND(13) TF_RND(15) TF_RND(26) TF_RND(6)
  x0 += ks2; x1 += ks0 + 5u;
#undef TF_RND
  o0 = x0; o1 = x1;
}

// ---------------- gumbel table: g[t][i], t<512, i<16384 (bit-identical) ----
__global__ __launch_bounds__(256) void gumbel_kernel(float* __restrict__ gt) {
  int idx = blockIdx.x * 256 + threadIdx.x;
  int t = idx >> 14, i = idx & 16383;
  uint32_t k0, k1;
  threefry2x32(0u, 42u, 0u, (uint32_t)t, k0, k1);
  uint32_t o0, o1;
  threefry2x32(k0, k1, 0u, (uint32_t)i, o0, o1);
  uint32_t bits = o0 ^ o1;
  uint32_t fb = (bits >> 9) | 0x3f800000u;
  float f = __uint_as_float(fb) - 1.0f;
  float u = (f == 0.f) ? 1.17549435e-38f : f;
  gt[idx] = (float)(-log(-log((double)u)));
}

// ---------------- embed ----------------
__global__ __launch_bounds__(256) void embed_kernel(const float* __restrict__ in,
    const float* __restrict__ w, const float* __restrict__ b, float* __restrict__ h) {
  int idx = blockIdx.x * 256 + threadIdx.x;
  int t = idx >> 7, e = idx & 127;
  h[idx] = in[t * 2] * w[e * 2] + in[t * 2 + 1] * w[e * 2 + 1] + b[e];
}

// ---------------- GEMM (R11 vectorized inner loop, bit-exact) ----------------
template<int OP>
__global__ __launch_bounds__(256) void gemm_kernel(const float* __restrict__ A,
    const float* __restrict__ W, const float* __restrict__ bias,
    const float* __restrict__ R, float* __restrict__ out, int N, int K) {
  __shared__ float As[64][36];
  __shared__ float Bs[64][36];
  int tid = threadIdx.x;
  int tx = tid & 15, ty = tid >> 4;
  int row0 = blockIdx.y * 64, col0 = blockIdx.x * 64;
  const int sa = (ty & 7) << 2, sb = (tx & 7) << 2;
  float acc[4][4] = {};
  for (int k0 = 0; k0 < K; k0 += 32) {
#pragma unroll
    for (int l = 0; l < 2; l++) {
      int idx = tid + l * 256;
      int r = idx >> 3, c = (idx & 7) * 4;
      int cs = c ^ (((r >> 2) & 7) << 2);
      *(float4*)&As[r][cs] = *(const float4*)&A[(size_t)(row0 + r) * K + k0 + c];
      *(float4*)&Bs[r][cs] = *(const float4*)&W[(size_t)(col0 + r) * K + k0 + c];
    }
    __syncthreads();
#pragma unroll
    for (int kq = 0; kq < 32; kq += 4) {
      float4 a4[4], b4[4];
#pragma unroll
      for (int u = 0; u < 4; u++) {
        a4[u] = *(const float4*)&As[ty * 4 + u][kq ^ sa];
        b4[u] = *(const float4*)&Bs[tx * 4 + u][kq ^ sb];
      }
      float aq[4][4], bq[4][4];
#pragma unroll
      for (int u = 0; u < 4; u++) {
        aq[u][0] = a4[u].x; aq[u][1] = a4[u].y; aq[u][2] = a4[u].z; aq[u][3] = a4[u].w;
        bq[u][0] = b4[u].x; bq[u][1] = b4[u].y; bq[u][2] = b4[u].z; bq[u][3] = b4[u].w;
      }
#pragma unroll
      for (int q = 0; q < 4; q++)
#pragma unroll
        for (int i = 0; i < 4; i++)
#pragma unroll
          for (int j = 0; j < 4; j++)
            acc[i][j] += aq[i][q] * bq[j][q];
    }
    __syncthreads();
  }
#pragma unroll
  for (int i = 0; i < 4; i++) {
    int r = row0 + ty * 4 + i;
#pragma unroll
    for (int j = 0; j < 4; j++) {
      int c = col0 + tx * 4 + j;
      float v = acc[i][j] + bias[c];
      if (OP == 1) v = fmaxf(v, 0.f);
      if (OP == 2) v += R[(size_t)r * N + c];
      if (OP == 3)      out[(((size_t)(c >> 2)) * 16384 + r) * 4 + (c & 3)] = v;
      else if (OP == 4) out[(((size_t)(r >> 2)) * N + c) * 4 + (r & 3)] = v;
      else              out[(size_t)r * N + c] = v;
    }
  }
}

// ---------------- weight transpose+interleave ----------------
__global__ __launch_bounds__(256) void wtr4_kernel(const float* __restrict__ in,
    float* __restrict__ out, int J, int K) {
  int idx = blockIdx.x * 256 + threadIdx.x;
  if (idx >= J * K) return;
  int j = idx / K, k = idx % K;
  out[((size_t)(k >> 2) * J + j) * 4 + (k & 3)] = in[(size_t)j * K + k];
}

// ---------------- vw split ----------------
__global__ __launch_bounds__(256) void wsplit_kernel(const float* __restrict__ in,
    float* __restrict__ outL, float* __restrict__ outR) {
  int idx = blockIdx.x * 256 + threadIdx.x;
  if (idx >= 16384) return;
  int j = idx >> 7, k = idx & 127;
  outL[idx] = in[(size_t)j * 256 + k];
  outR[idx] = in[(size_t)j * 256 + 128 + k];
}

// ---------------- encoder self-attention, q-split (R15, bit-exact) ----------------
#define ATTN_LDS_FLOATS (2*512*33 + 128 + 4*513 + 512)
__global__ __launch_bounds__(256) void attn_kernel(const float* __restrict__ qkv,
                                                   float* __restrict__ aout) {
  extern __shared__ float sm[];
  float* Ks = sm;
  float* Vs = Ks + 512 * 33;
  float* qs = Vs + 512 * 33;
  float* P  = qs + 128;
  float* red = P + 4 * 513;
  int tid = threadIdx.x;
  int lane = tid & 63, wv = tid >> 6;
  int b = blockIdx.x >> 3, h = (blockIdx.x >> 1) & 3, qh = blockIdx.x & 1;
  const float scale = 0.17677669529663687f;
  const size_t base = (size_t)b * 512 * 384;
  for (int idx = tid; idx < 512 * 32; idx += 256) {
    int s = idx >> 5, d = idx & 31;
    Ks[s * 33 + d] = qkv[base + (size_t)s * 384 + 128 + h * 32 + d];
    Vs[s * 33 + d] = qkv[base + (size_t)s * 384 + 256 + h * 32 + d];
  }
  __syncthreads();
  for (int q0 = qh * 256; q0 < qh * 256 + 256; q0 += 4) {
    if (tid < 128) {
      int r = tid >> 5, d = tid & 31;
      qs[r * 32 + d] = qkv[base + (size_t)(q0 + r) * 384 + h * 32 + d] * scale;
    }
    __syncthreads();
    for (int s = tid; s < 512; s += 256) {
      float a0 = 0, a1 = 0, a2 = 0, a3 = 0;
      const float* kr = Ks + s * 33;
#pragma unroll 8
      for (int d = 0; d < 32; d++) {
        float kv = kr[d];
        a0 += qs[d] * kv; a1 += qs[32 + d] * kv; a2 += qs[64 + d] * kv; a3 += qs[96 + d] * kv;
      }
      P[0 * 513 + s] = a0; P[1 * 513 + s] = a1; P[2 * 513 + s] = a2; P[3 * 513 + s] = a3;
    }
    __syncthreads();
    float v0[4], v1[4], mx[4], sums[4];
#pragma unroll
    for (int r = 0; r < 4; r++) { v0[r] = P[r * 513 + tid]; v1[r] = P[r * 513 + tid + 256]; }
#pragma unroll
    for (int r = 0; r < 4; r++) {
      float x = fmaxf(v0[r], v1[r]);
      for (int off = 32; off; off >>= 1) x = fmaxf(x, __shfl_xor(x, off));
      if (lane == 0) red[wv * 4 + r] = x;
    }
    __syncthreads();
#pragma unroll
    for (int r = 0; r < 4; r++) {
      float x = red[r];
      for (int w = 1; w < 4; w++) x = fmaxf(x, red[w * 4 + r]);
      mx[r] = x;
    }
    __syncthreads();
#pragma unroll
    for (int r = 0; r < 4; r++) {
      float e0 = expf(v0[r] - mx[r]), e1 = expf(v1[r] - mx[r]);
      P[r * 513 + tid] = e0; P[r * 513 + tid + 256] = e1;
      float x = e0 + e1;
      for (int off = 32; off; off >>= 1) x += __shfl_xor(x, off);
      if (lane == 0) red[wv * 4 + r] = x;
    }
    __syncthreads();
#pragma unroll
    for (int r = 0; r < 4; r++) {
      float x = 0;
      for (int w = 0; w < 4; w++) x += red[w * 4 + r];
      sums[r] = x;
    }
#pragma unroll
    for (int r = 0; r < 4; r++) {
      P[r * 513 + tid] /= sums[r];
      P[r * 513 + tid + 256] /= sums[r];
    }
    __syncthreads();
    {
      int d = tid & 31, p = tid >> 5;
      float a0 = 0, a1 = 0, a2 = 0, a3 = 0;
#pragma unroll 4
      for (int i = 0; i < 64; i++) {
        int s = p * 64 + i;
        float vv = Vs[s * 33 + d];
        a0 += P[0 * 513 + s] * vv; a1 += P[1 * 513 + s] * vv;
        a2 += P[2 * 513 + s] * vv; a3 += P[3 * 513 + s] * vv;
      }
      a0 += __shfl_xor(a0, 32); a1 += __shfl_xor(a1, 32);
      a2 += __shfl_xor(a2, 32); a3 += __shfl_xor(a3, 32);
      if (lane < 32) {
        red[wv * 128 + 0 * 32 + d] = a0;
        red[wv * 128 + 1 * 32 + d] = a1;
        red[wv * 128 + 2 * 32 + d] = a2;
        red[wv * 128 + 3 * 32 + d] = a3;
      }
    }
    __syncthreads();
    if (tid < 128) {
      int r = tid >> 5, d = tid & 31;
      float x = red[0 * 128 + r * 32 + d] + red[1 * 128 + r * 32 + d]
              + red[2 * 128 + r * 32 + d] + red[3 * 128 + r * 32 + d];
      aout[(size_t)(b * 512 + q0 + r) * 128 + h * 32 + d] = x;
    }
    __syncthreads();
  }
}

// ---------------- h_bar ----------------
__global__ __launch_bounds__(128) void hbar_kernel(const float* __restrict__ h,
    const float* __restrict__ hctx_w, const float* __restrict__ hctx_b,
    float* __restrict__ h_bar) {
  __shared__ float m[128];
  int b = blockIdx.x, e = threadIdx.x;
  float s = 0.f;
  for (int t = 0; t < 512; t++) s += h[((size_t)b * 512 + t) * 128 + e];
  m[e] = s * (1.0f / 512.0f);
  __syncthreads();
  float acc = hctx_b[e];
  for (int k = 0; k < 128; k++) acc += m[k] * hctx_w[e * 128 + k];
  h_bar[b * 128 + e] = acc;
}

// ---------------- vproj ----------------
__global__ __launch_bounds__(128) void vproj_kernel(const float* __restrict__ init_w,
    const float* __restrict__ vw_w, const float* __restrict__ vw_b,
    float* __restrict__ vproj) {
  int j = threadIdx.x;
  float acc = vw_b[j];
  for (int k = 0; k < 256; k++) acc += init_w[k] * vw_w[j * 256 + k];
  vproj[j] = acc;
}

// ---------------- decode: R13 structure + wqT/wpT cached in LDS (bit-exact) ----
// Dynamic LDS: wq_lds 64KB + wp_lds 64KB + working set ~18.4KB = ~146KB.
#define DEC_LDS_FLOATS (16384 + 16384 + 6*128 + 512 + 2048 + 512 + 512 + 128 + 64 + 32)
__global__ __launch_bounds__(512) void decode_kernel(
    const float* __restrict__ gv4, const float* __restrict__ gkT4,
    const float* __restrict__ pkT4, const float* __restrict__ h_bar,
    const float* __restrict__ vproj,
    const float* __restrict__ gq_wT, const float* __restrict__ gq_b,
    const float* __restrict__ go_wT, const float* __restrict__ go_b,
    const float* __restrict__ pq_wT, const float* __restrict__ pq_b,
    const float* __restrict__ vw_b, const float* __restrict__ gt,
    const float* __restrict__ P2L, const float* __restrict__ P2R,
    float* __restrict__ out) {
  extern __shared__ float dsm[];
  float* wq_lds  = dsm;                    // 16384
  float* wp_lds  = wq_lds + 16384;         // 16384
  float* query   = wp_lds + 16384;         // 128
  float* hbar_s  = query + 128;
  float* gqv     = hbar_s + 128;
  float* nq      = gqv + 128;
  float* nq2     = nq + 128;
  float* pqv     = nq2 + 128;
  float* part    = pqv + 128;              // 512
  float* gl      = part + 512;             // 2048
  float* pl      = gl + 2048;              // 512
  int*   mask    = (int*)(pl + 512);       // 512
  int*   qmask   = (int*)(mask + 512);     // 128
  float* redf    = (float*)(qmask + 128);  // 32
  float* redf2   = redf + 32;              // 32
  float* redv    = redf2 + 32;             // 8
  int*   redi    = (int*)(redv + 8);       // 8
  float* redm2   = (float*)(redi + 8);     // 8
  float* reds2   = redm2 + 8;              // 8

  int b = blockIdx.x;
  int tid = threadIdx.x;
  int lane = tid & 63, wave = tid >> 6;      // 8 waves
  int j = tid & 127, p = tid >> 7;           // 4 p-groups x 128 j

  const float4* gv4b = (const float4*)gv4 + (size_t)b * 16384;   // idx q*128+j
  const float4* gk4  = (const float4*)gkT4 + (size_t)b * 512;    // idx c*16384+s
  const float4* pk4  = (const float4*)pkT4 + (size_t)b * 512;
  const float*  gtb  = gt + (size_t)b * 512;
  const float*  p2lB = P2L + (size_t)b * 65536;
  const float*  p2rB = P2R + (size_t)b * 65536;

  // preload gq_wT and pq_wT into LDS (same layout, bit-identical values)
  for (int idx = tid; idx < 16384; idx += 512) {
    wq_lds[idx] = gq_wT[idx];
    wp_lds[idx] = pq_wT[idx];
  }
  if (tid < 128) {
    float hbv = h_bar[b * 128 + tid];
    hbar_s[tid] = hbv;
    query[tid] = hbv + vproj[tid];
    qmask[tid] = 0;
  }
  mask[tid] = 0;
  int fc = 0;   // first chosen index (set at t==0; identical across threads)
  __syncthreads();

  for (int t = 0; t < 512; t++) {
    float gum = gtb[(size_t)t * 16384 + tid];   // hoisted; completes by phase B

    // A: gq partials from LDS-cached weights (k = p*32 + 4i + comp, ascending)
    {
      const float4* q4 = (const float4*)query + p * 8;
      const float4* w4 = (const float4*)wq_lds + (size_t)(p * 8) * 128 + j;
      float acc = 0.f;
#pragma unroll
      for (int i = 0; i < 8; i++) {
        float4 x4 = q4[i]; float4 ww = w4[(size_t)i * 128];
        acc += x4.x * ww.x; acc += x4.y * ww.y; acc += x4.z * ww.z; acc += x4.w * ww.w;
      }
      part[p * 128 + j] = acc;
    }
    __syncthreads();
    // B: gqv combine ((p0+p1)+(p2+p3)) + bias
    if (tid < 128)
      gqv[tid] = (part[tid] + part[128 + tid]) + (part[256 + tid] + part[384 + tid]) + gq_b[tid];
    __syncthreads();

    // C: glimpse logits (s = tid), wave max; masked lanes skip loads (dot unused)
    float v[4];
    {
      bool msk = (mask[tid] != 0);
      if (!msk) {
        const float4* q4 = (const float4*)gqv;
#pragma unroll
        for (int hh = 0; hh < 4; hh++) {
          float acc = 0.f;
#pragma unroll
          for (int i = 0; i < 8; i++) {
            float4 qq = q4[hh * 8 + i];
            float4 gg = gk4[(size_t)(hh * 8 + i) * 16384 + tid];
            acc += qq.x * gg.x; acc += qq.y * gg.y; acc += qq.z * gg.z; acc += qq.w * gg.w;
          }
          v[hh] = acc * 0.17677669529663687f;
        }
      } else {
        v[0] = v[1] = v[2] = v[3] = NEGV;
      }
#pragma unroll
      for (int hh = 0; hh < 4; hh++) {
        float x = v[hh];
        for (int off = 32; off; off >>= 1) x = fmaxf(x, __shfl_xor(x, off));
        if (lane == 0) redf[wave * 4 + hh] = x;
      }
    }
    __syncthreads();
    // D: combine max, exp, wave sums
    float e[4];
    {
#pragma unroll
      for (int hh = 0; hh < 4; hh++) {
        float x = redf[hh];
        for (int w = 1; w < 8; w++) x = fmaxf(x, redf[w * 4 + hh]);
        e[hh] = expf(v[hh] - x);
        float sx = e[hh];
        for (int off = 32; off; off >>= 1) sx += __shfl_xor(sx, off);
        if (lane == 0) redf2[wave * 4 + hh] = sx;
      }
    }
    __syncthreads();
    // E: combine sums, write alpha
    {
#pragma unroll
      for (int hh = 0; hh < 4; hh++) {
        float x = 0.f;
        for (int w = 0; w < 8; w++) x += redf2[w * 4 + hh];
        gl[hh * 512 + tid] = e[hh] / x;
      }
    }
    __syncthreads();

    // F: nq partials (i ascending within p), skip fully-masked quads (alpha==+0)
    {
      int hh = j >> 5;
      const float4* al4 = (const float4*)(gl + hh * 512 + p * 128);
      const float4* gp  = gv4b + (size_t)(p * 32) * 128 + j;
      const int* qm = qmask + p * 32;
      float acc = 0.f;
#pragma unroll 4
      for (int i = 0; i < 32; i++) {
        if (!qm[i]) {
          float4 aa = al4[i]; float4 vv = gp[(size_t)i * 128];
          acc += aa.x * vv.x; acc += aa.y * vv.y; acc += aa.z * vv.z; acc += aa.w * vv.w;
        }
      }
      part[p * 128 + j] = acc;
    }
    __syncthreads();
    // G: nq combine (no bias)
    if (tid < 128)
      nq[tid] = (part[tid] + part[128 + tid]) + (part[256 + tid] + part[384 + tid]);
    __syncthreads();

    // H: go partials (global weights)
    {
      const float4* q4 = (const float4*)nq + p * 8;
      const float4* w4 = (const float4*)go_wT + (size_t)(p * 8) * 128 + j;
      float acc = 0.f;
#pragma unroll
      for (int i = 0; i < 8; i++) {
        float4 x4 = q4[i]; float4 ww = w4[(size_t)i * 128];
        acc += x4.x * ww.x; acc += x4.y * ww.y; acc += x4.z * ww.z; acc += x4.w * ww.w;
      }
      part[p * 128 + j] = acc;
    }
    __syncthreads();
    // I: nq2 combine
    if (tid < 128)
      nq2[tid] = (part[tid] + part[128 + tid]) + (part[256 + tid] + part[384 + tid]) + go_b[tid];
    __syncthreads();

    // J: pq partials from LDS-cached weights
    {
      const float4* q4 = (const float4*)nq2 + p * 8;
      const float4* w4 = (const float4*)wp_lds + (size_t)(p * 8) * 128 + j;
      float acc = 0.f;
#pragma unroll
      for (int i = 0; i < 8; i++) {
        float4 x4 = q4[i]; float4 ww = w4[(size_t)i * 128];
        acc += x4.x * ww.x; acc += x4.y * ww.y; acc += x4.z * ww.z; acc += x4.w * ww.w;
      }
      part[p * 128 + j] = acc;
    }
    __syncthreads();
    // K: pqv combine
    if (tid < 128)
      pqv[tid] = (part[tid] + part[128 + tid]) + (part[256 + tid] + part[384 + tid]) + pq_b[tid];
    __syncthreads();

    // L: pointer logits (s = tid) + gumbel; masked lanes skip loads+tanh
    {
      bool msk = (mask[tid] != 0);
      float plv;
      if (!msk) {
        const float4* q4 = (const float4*)pqv;
        float acc = 0.f;
#pragma unroll 8
        for (int i = 0; i < 32; i++) {
          float4 qq = q4[i];
          float4 pp = pk4[(size_t)i * 16384 + tid];
          acc += qq.x * pp.x; acc += qq.y * pp.y; acc += qq.z * pp.z; acc += qq.w * pp.w;
        }
        plv = 10.0f * tanhf(acc * 0.08838834764831843f);
      } else {
        plv = NEGV;
      }
      pl[tid] = plv;
      float pgv = plv + gum;
      float av = pgv; int ix = tid;
      float mp = plv;
      for (int off = 32; off; off >>= 1) {
        float ov = __shfl_xor(av, off); int oi = __shfl_xor(ix, off);
        if (ov > av || (ov == av && oi < ix)) { av = ov; ix = oi; }
        mp = fmaxf(mp, __shfl_xor(mp, off));
      }
      float ee = expf(plv - mp);
      for (int off = 32; off; off >>= 1) ee += __shfl_xor(ee, off);
      if (lane == 0) { redv[wave] = av; redi[wave] = ix; redm2[wave] = mp; reds2[wave] = ee; }
    }
    __syncthreads();

    // M: combine argmax (all threads, deterministic); outputs; mask + qmask update
    int c;
    {
      float av = redv[0]; c = redi[0];
#pragma unroll
      for (int w = 1; w < 8; w++) {
        if (redv[w] > av || (redv[w] == av && redi[w] < c)) { av = redv[w]; c = redi[w]; }
      }
      if (t == 0) fc = c;
      if (tid == 0) {
        float M = redm2[0];
        for (int w = 1; w < 8; w++) M = fmaxf(M, redm2[w]);
        float S = 0.f;
        for (int w = 0; w < 8; w++) S += reds2[w] * expf(redm2[w] - M);
        out[b * 512 + t] = pl[c] - M - logf(S);
        out[16384 + b * 512 + t] = (float)c;
        mask[c] = 1;
        int q = c >> 2;
        qmask[q] = mask[q * 4] & mask[q * 4 + 1] & mask[q * 4 + 2] & mask[q * 4 + 3];
      }
    }
    __syncthreads();

    // O': query = hbar + ((P2L[fc] + P2R[c]) + vw_b)
    if (tid < 128) {
      float p2 = p2lB[(size_t)fc * 128 + tid] + p2rB[(size_t)c * 128 + tid];
      query[tid] = hbar_s[tid] + (p2 + vw_b[tid]);
    }
    __syncthreads();
  }
}

// ---------------- launch ----------------
extern "C" void kernel_launch(void* const* d_in, const int* in_sizes, int n_in,
                              void* d_out, int out_size, void* d_ws, size_t ws_size,
                              hipStream_t stream) {
  (void)in_sizes; (void)n_in; (void)out_size; (void)ws_size;
  const float* inputs     = (const float*)d_in[0];
  const float* emb_w      = (const float*)d_in[1];
  const float* emb_b      = (const float*)d_in[2];
  const float* in_proj_w  = (const float*)d_in[3];
  const float* in_proj_b  = (const float*)d_in[4];
  const float* out_proj_w = (const float*)d_in[5];
  const float* out_proj_b = (const float*)d_in[6];
  const float* ff1_w      = (const float*)d_in[7];
  const float* ff1_b      = (const float*)d_in[8];
  const float* ff2_w      = (const float*)d_in[9];
  const float* ff2_b      = (const float*)d_in[10];
  const float* hctx_w     = (const float*)d_in[11];
  const float* hctx_b     = (const float*)d_in[12];
  const float* vw_w       = (const float*)d_in[13];
  const float* vw_b       = (const float*)d_in[14];
  const float* init_w     = (const float*)d_in[15];
  const float* gq_w = (const float*)d_in[16]; const float* gq_b = (const float*)d_in[17];
  const float* gk_w = (const float*)d_in[18]; const float* gk_b = (const float*)d_in[19];
  const float* gv_w = (const float*)d_in[20]; const float* gv_b = (const float*)d_in[21];
  const float* go_w = (const float*)d_in[22]; const float* go_b = (const float*)d_in[23];
  const float* pq_w = (const float*)d_in[24]; const float* pq_b = (const float*)d_in[25];
  const float* pk_w = (const float*)d_in[26]; const float* pk_b = (const float*)d_in[27];
  float* out = (float*)d_out;

  float* ws   = (float*)d_ws;
  float* h    = ws;                       // 2,097,152
  float* s1   = h + 2097152;              // 8,388,608 encoder scratch
  float* s2   = s1 + 8388608;             // 2,097,152 (attn out; later gkT4)
  float* hbar = s2 + 2097152;             // 4096
  float* vpj  = hbar + 4096;              // 128
  float* wqT  = vpj + 128;                // 16384
  float* woT  = wqT + 16384;              // 16384
  float* wpT  = woT + 16384;              // 16384
  float* vwL  = wpT + 16384;              // 16384
  float* vwR  = vwL + 16384;              // 16384
  float* zeros= vwR + 16384;              // 128
  float* gtab = zeros + 128;              // 8,388,608
  // decode-time overlays of s1 (dead after encoder):
  float* P2Lb = s1;                       // 2,097,152
  float* gv4  = s1 + 2097152;             // 2,097,152
  float* pkT4 = s1 + 4194304;             // 2,097,152
  float* P2Rb = s1 + 6291456;             // 2,097,152
  float* gkT4 = s2;                       // 2,097,152

  const int attn_lds = ATTN_LDS_FLOATS * 4;
  hipFuncSetAttribute((const void*)attn_kernel,
                      hipFuncAttributeMaxDynamicSharedMemorySize, attn_lds);
  const int dec_lds = DEC_LDS_FLOATS * 4;
  hipFuncSetAttribute((const void*)decode_kernel,
                      hipFuncAttributeMaxDynamicSharedMemorySize, dec_lds);

  gumbel_kernel<<<32768, 256, 0, stream>>>(gtab);
  embed_kernel<<<8192, 256, 0, stream>>>(inputs, emb_w, emb_b, h);
  for (int l = 0; l < 2; l++) {
    gemm_kernel<0><<<dim3(6, 256), 256, 0, stream>>>(
        h, in_proj_w + (size_t)l * 384 * 128, in_proj_b + l * 384, nullptr, s1, 384, 128);
    attn_kernel<<<256, 256, attn_lds, stream>>>(s1, s2);
    gemm_kernel<2><<<dim3(2, 256), 256, 0, stream>>>(
        s2, out_proj_w + (size_t)l * 128 * 128, out_proj_b + l * 128, h, h, 128, 128);
    gemm_kernel<1><<<dim3(8, 256), 256, 0, stream>>>(
        h, ff1_w + (size_t)l * 512 * 128, ff1_b + l * 512, nullptr, s1, 512, 128);
    gemm_kernel<2><<<dim3(2, 256), 256, 0, stream>>>(
        s1, ff2_w + (size_t)l * 128 * 512, ff2_b + l * 128, h, h, 128, 512);
  }
  // decode operand prep (identical layouts to R13/R15)
  hipMemsetAsync(zeros, 0, 512, stream);
  gemm_kernel<3><<<dim3(2, 256), 256, 0, stream>>>(h, gk_w, gk_b, nullptr, gkT4, 128, 128);
  gemm_kernel<4><<<dim3(2, 256), 256, 0, stream>>>(h, gv_w, gv_b, nullptr, gv4, 128, 128);
  gemm_kernel<3><<<dim3(2, 256), 256, 0, stream>>>(h, pk_w, pk_b, nullptr, pkT4, 128, 128);
  wtr4_kernel<<<64, 256, 0, stream>>>(gq_w, wqT, 128, 128);
  wtr4_kernel<<<64, 256, 0, stream>>>(go_w, woT, 128, 128);
  wtr4_kernel<<<64, 256, 0, stream>>>(pq_w, wpT, 128, 128);
  wsplit_kernel<<<64, 256, 0, stream>>>(vw_w, vwL, vwR);
  gemm_kernel<0><<<dim3(2, 256), 256, 0, stream>>>(h, vwL, zeros, nullptr, P2Lb, 128, 128);
  gemm_kernel<0><<<dim3(2, 256), 256, 0, stream>>>(h, vwR, zeros, nullptr, P2Rb, 128, 128);
  hbar_kernel<<<32, 128, 0, stream>>>(h, hctx_w, hctx_b, hbar);
  vproj_kernel<<<1, 128, 0, stream>>>(init_w, vw_w, vw_b, vpj);
  decode_kernel<<<32, 512, dec_lds, stream>>>(gv4, gkT4, pkT4, hbar, vpj,
      wqT, gq_b, woT, go_b, wpT, pq_b, vw_b, gtab, P2Lb, P2Rb, out);
}

// Round 17
// 10656.127 us; speedup vs baseline: 1.0344x; 1.0344x over previous
//
#include <hip/hip_runtime.h>
#include <hip/hip_bf16.h>
#include <cstdint>

#define NEGV  (-1e9f)

// ---------------- threefry2x32 (exact JAX semantics) ----------------
__device__ __forceinline__ void threefry2x32(uint32_t k0, uint32_t k1,
                                             uint32_t x0, uint32_t x1,
                                             uint32_t& o0, uint32_t& o1) {
  uint32_t ks0 = k0, ks1 = k1, ks2 = k0 ^ k1 ^ 0x1BD11BDAu;
  x0 += ks0; x1 += ks1;
#define TF_RND(r) { x0 += x1; x1 = (x1 << (r)) | (x1 >> (32 - (r))); x1 ^= x0; }
  TF_RND(13) TF_RND(15) TF_RND(26) TF_RND(6)
  x0 += ks1; x1 += ks2 + 1u;
  TF_RND(17) TF_RND(29) TF_RND(16) TF_RND(24)
  x0 += ks2; x1 += ks0 + 2u;
  TF_RND(13) TF_RND(15) TF_RND(26) TF_RND(6)
  x0 += ks0; x1 += ks1 + 3u;
  TF_RND(17) TF_RND(29) TF_RND(16) TF_RND(24)
  x0 += ks1; x1 += ks2 + 4u;
  TF_RND(13) TF_RND(15) TF_RND(26) TF_RND(6)
  x0 += ks2; x1 += ks0 + 5u;
#undef TF_RND
  o0 = x0; o1 = x1;
}

// ---------------- gumbel table: g[t][i], t<512, i<16384 (bit-identical) ----
__global__ __launch_bounds__(256) void gumbel_kernel(float* __restrict__ gt) {
  int idx = blockIdx.x * 256 + threadIdx.x;
  int t = idx >> 14, i = idx & 16383;
  uint32_t k0, k1;
  threefry2x32(0u, 42u, 0u, (uint32_t)t, k0, k1);
  uint32_t o0, o1;
  threefry2x32(k0, k1, 0u, (uint32_t)i, o0, o1);
  uint32_t bits = o0 ^ o1;
  uint32_t fb = (bits >> 9) | 0x3f800000u;
  float f = __uint_as_float(fb) - 1.0f;
  float u = (f == 0.f) ? 1.17549435e-38f : f;
  gt[idx] = (float)(-log(-log((double)u)));
}

// ---------------- embed ----------------
__global__ __launch_bounds__(256) void embed_kernel(const float* __restrict__ in,
    const float* __restrict__ w, const float* __restrict__ b, float* __restrict__ h) {
  int idx = blockIdx.x * 256 + threadIdx.x;
  int t = idx >> 7, e = idx & 127;
  h[idx] = in[t * 2] * w[e * 2] + in[t * 2 + 1] * w[e * 2 + 1] + b[e];
}

// ---------------- GEMM (R11 vectorized inner loop, bit-exact) ----------------
template<int OP>
__global__ __launch_bounds__(256) void gemm_kernel(const float* __restrict__ A,
    const float* __restrict__ W, const float* __restrict__ bias,
    const float* __restrict__ R, float* __restrict__ out, int N, int K) {
  __shared__ float As[64][36];
  __shared__ float Bs[64][36];
  int tid = threadIdx.x;
  int tx = tid & 15, ty = tid >> 4;
  int row0 = blockIdx.y * 64, col0 = blockIdx.x * 64;
  const int sa = (ty & 7) << 2, sb = (tx & 7) << 2;
  float acc[4][4] = {};
  for (int k0 = 0; k0 < K; k0 += 32) {
#pragma unroll
    for (int l = 0; l < 2; l++) {
      int idx = tid + l * 256;
      int r = idx >> 3, c = (idx & 7) * 4;
      int cs = c ^ (((r >> 2) & 7) << 2);
      *(float4*)&As[r][cs] = *(const float4*)&A[(size_t)(row0 + r) * K + k0 + c];
      *(float4*)&Bs[r][cs] = *(const float4*)&W[(size_t)(col0 + r) * K + k0 + c];
    }
    __syncthreads();
#pragma unroll
    for (int kq = 0; kq < 32; kq += 4) {
      float4 a4[4], b4[4];
#pragma unroll
      for (int u = 0; u < 4; u++) {
        a4[u] = *(const float4*)&As[ty * 4 + u][kq ^ sa];
        b4[u] = *(const float4*)&Bs[tx * 4 + u][kq ^ sb];
      }
      float aq[4][4], bq[4][4];
#pragma unroll
      for (int u = 0; u < 4; u++) {
        aq[u][0] = a4[u].x; aq[u][1] = a4[u].y; aq[u][2] = a4[u].z; aq[u][3] = a4[u].w;
        bq[u][0] = b4[u].x; bq[u][1] = b4[u].y; bq[u][2] = b4[u].z; bq[u][3] = b4[u].w;
      }
#pragma unroll
      for (int q = 0; q < 4; q++)
#pragma unroll
        for (int i = 0; i < 4; i++)
#pragma unroll
          for (int j = 0; j < 4; j++)
            acc[i][j] += aq[i][q] * bq[j][q];
    }
    __syncthreads();
  }
#pragma unroll
  for (int i = 0; i < 4; i++) {
    int r = row0 + ty * 4 + i;
#pragma unroll
    for (int j = 0; j < 4; j++) {
      int c = col0 + tx * 4 + j;
      float v = acc[i][j] + bias[c];
      if (OP == 1) v = fmaxf(v, 0.f);
      if (OP == 2) v += R[(size_t)r * N + c];
      if (OP == 3)      out[(((size_t)(c >> 2)) * 16384 + r) * 4 + (c & 3)] = v;
      else if (OP == 4) out[(((size_t)(r >> 2)) * N + c) * 4 + (r & 3)] = v;
      else              out[(size_t)r * N + c] = v;
    }
  }
}

// ---------------- weight transpose+interleave ----------------
__global__ __launch_bounds__(256) void wtr4_kernel(const float* __restrict__ in,
    float* __restrict__ out, int J, int K) {
  int idx = blockIdx.x * 256 + threadIdx.x;
  if (idx >= J * K) return;
  int j = idx / K, k = idx % K;
  out[((size_t)(k >> 2) * J + j) * 4 + (k & 3)] = in[(size_t)j * K + k];
}

// ---------------- vw split ----------------
__global__ __launch_bounds__(256) void wsplit_kernel(const float* __restrict__ in,
    float* __restrict__ outL, float* __restrict__ outR) {
  int idx = blockIdx.x * 256 + threadIdx.x;
  if (idx >= 16384) return;
  int j = idx >> 7, k = idx & 127;
  outL[idx] = in[(size_t)j * 256 + k];
  outR[idx] = in[(size_t)j * 256 + 128 + k];
}

// ---------------- encoder self-attention, q-split (R15, bit-exact) ----------------
#define ATTN_LDS_FLOATS (2*512*33 + 128 + 4*513 + 512)
__global__ __launch_bounds__(256) void attn_kernel(const float* __restrict__ qkv,
                                                   float* __restrict__ aout) {
  extern __shared__ float sm[];
  float* Ks = sm;
  float* Vs = Ks + 512 * 33;
  float* qs = Vs + 512 * 33;
  float* P  = qs + 128;
  float* red = P + 4 * 513;
  int tid = threadIdx.x;
  int lane = tid & 63, wv = tid >> 6;
  int b = blockIdx.x >> 3, h = (blockIdx.x >> 1) & 3, qh = blockIdx.x & 1;
  const float scale = 0.17677669529663687f;
  const size_t base = (size_t)b * 512 * 384;
  for (int idx = tid; idx < 512 * 32; idx += 256) {
    int s = idx >> 5, d = idx & 31;
    Ks[s * 33 + d] = qkv[base + (size_t)s * 384 + 128 + h * 32 + d];
    Vs[s * 33 + d] = qkv[base + (size_t)s * 384 + 256 + h * 32 + d];
  }
  __syncthreads();
  for (int q0 = qh * 256; q0 < qh * 256 + 256; q0 += 4) {
    if (tid < 128) {
      int r = tid >> 5, d = tid & 31;
      qs[r * 32 + d] = qkv[base + (size_t)(q0 + r) * 384 + h * 32 + d] * scale;
    }
    __syncthreads();
    for (int s = tid; s < 512; s += 256) {
      float a0 = 0, a1 = 0, a2 = 0, a3 = 0;
      const float* kr = Ks + s * 33;
#pragma unroll 8
      for (int d = 0; d < 32; d++) {
        float kv = kr[d];
        a0 += qs[d] * kv; a1 += qs[32 + d] * kv; a2 += qs[64 + d] * kv; a3 += qs[96 + d] * kv;
      }
      P[0 * 513 + s] = a0; P[1 * 513 + s] = a1; P[2 * 513 + s] = a2; P[3 * 513 + s] = a3;
    }
    __syncthreads();
    float v0[4], v1[4], mx[4], sums[4];
#pragma unroll
    for (int r = 0; r < 4; r++) { v0[r] = P[r * 513 + tid]; v1[r] = P[r * 513 + tid + 256]; }
#pragma unroll
    for (int r = 0; r < 4; r++) {
      float x = fmaxf(v0[r], v1[r]);
      for (int off = 32; off; off >>= 1) x = fmaxf(x, __shfl_xor(x, off));
      if (lane == 0) red[wv * 4 + r] = x;
    }
    __syncthreads();
#pragma unroll
    for (int r = 0; r < 4; r++) {
      float x = red[r];
      for (int w = 1; w < 4; w++) x = fmaxf(x, red[w * 4 + r]);
      mx[r] = x;
    }
    __syncthreads();
#pragma unroll
    for (int r = 0; r < 4; r++) {
      float e0 = expf(v0[r] - mx[r]), e1 = expf(v1[r] - mx[r]);
      P[r * 513 + tid] = e0; P[r * 513 + tid + 256] = e1;
      float x = e0 + e1;
      for (int off = 32; off; off >>= 1) x += __shfl_xor(x, off);
      if (lane == 0) red[wv * 4 + r] = x;
    }
    __syncthreads();
#pragma unroll
    for (int r = 0; r < 4; r++) {
      float x = 0;
      for (int w = 0; w < 4; w++) x += red[w * 4 + r];
      sums[r] = x;
    }
#pragma unroll
    for (int r = 0; r < 4; r++) {
      P[r * 513 + tid] /= sums[r];
      P[r * 513 + tid + 256] /= sums[r];
    }
    __syncthreads();
    {
      int d = tid & 31, p = tid >> 5;
      float a0 = 0, a1 = 0, a2 = 0, a3 = 0;
#pragma unroll 4
      for (int i = 0; i < 64; i++) {
        int s = p * 64 + i;
        float vv = Vs[s * 33 + d];
        a0 += P[0 * 513 + s] * vv; a1 += P[1 * 513 + s] * vv;
        a2 += P[2 * 513 + s] * vv; a3 += P[3 * 513 + s] * vv;
      }
      a0 += __shfl_xor(a0, 32); a1 += __shfl_xor(a1, 32);
      a2 += __shfl_xor(a2, 32); a3 += __shfl_xor(a3, 32);
      if (lane < 32) {
        red[wv * 128 + 0 * 32 + d] = a0;
        red[wv * 128 + 1 * 32 + d] = a1;
        red[wv * 128 + 2 * 32 + d] = a2;
        red[wv * 128 + 3 * 32 + d] = a3;
      }
    }
    __syncthreads();
    if (tid < 128) {
      int r = tid >> 5, d = tid & 31;
      float x = red[0 * 128 + r * 32 + d] + red[1 * 128 + r * 32 + d]
              + red[2 * 128 + r * 32 + d] + red[3 * 128 + r * 32 + d];
      aout[(size_t)(b * 512 + q0 + r) * 128 + h * 32 + d] = x;
    }
    __syncthreads();
  }
}

// ---------------- h_bar ----------------
__global__ __launch_bounds__(128) void hbar_kernel(const float* __restrict__ h,
    const float* __restrict__ hctx_w, const float* __restrict__ hctx_b,
    float* __restrict__ h_bar) {
  __shared__ float m[128];
  int b = blockIdx.x, e = threadIdx.x;
  float s = 0.f;
  for (int t = 0; t < 512; t++) s += h[((size_t)b * 512 + t) * 128 + e];
  m[e] = s * (1.0f / 512.0f);
  __syncthreads();
  float acc = hctx_b[e];
  for (int k = 0; k < 128; k++) acc += m[k] * hctx_w[e * 128 + k];
  h_bar[b * 128 + e] = acc;
}

// ---------------- vproj ----------------
__global__ __launch_bounds__(128) void vproj_kernel(const float* __restrict__ init_w,
    const float* __restrict__ vw_w, const float* __restrict__ vw_b,
    float* __restrict__ vproj) {
  int j = threadIdx.x;
  float acc = vw_b[j];
  for (int k = 0; k < 256; k++) acc += init_w[k] * vw_w[j * 256 + k];
  vproj[j] = acc;
}

// ---------------- decode: R15 + O' merged into M (13 barriers) + P2L[fc] reg cache ----
__global__ __launch_bounds__(512) void decode_kernel(
    const float* __restrict__ gv4, const float* __restrict__ gkT4,
    const float* __restrict__ pkT4, const float* __restrict__ h_bar,
    const float* __restrict__ vproj,
    const float* __restrict__ gq_wT, const float* __restrict__ gq_b,
    const float* __restrict__ go_wT, const float* __restrict__ go_b,
    const float* __restrict__ pq_wT, const float* __restrict__ pq_b,
    const float* __restrict__ vw_b, const float* __restrict__ gt,
    const float* __restrict__ P2L, const float* __restrict__ P2R,
    float* __restrict__ out) {
  int b = blockIdx.x;
  int tid = threadIdx.x;
  int lane = tid & 63, wave = tid >> 6;      // 8 waves
  int j = tid & 127, p = tid >> 7;           // 4 p-groups x 128 j
  __shared__ float query[128], hbar_s[128], gqv[128], nq[128], nq2[128], pqv[128];
  __shared__ float part[512];
  __shared__ float gl[4 * 512];
  __shared__ float pl[512];
  __shared__ int   mask[512];
  __shared__ int   qmask[128];
  __shared__ float redf[32], redf2[32];
  __shared__ float redv[8]; __shared__ int redi[8];
  __shared__ float redm2[8], reds2[8];

  const float4* gv4b = (const float4*)gv4 + (size_t)b * 16384;   // idx q*128+j
  const float4* gk4  = (const float4*)gkT4 + (size_t)b * 512;    // idx c*16384+s
  const float4* pk4  = (const float4*)pkT4 + (size_t)b * 512;
  const float*  gtb  = gt + (size_t)b * 512;
  const float*  p2lB = P2L + (size_t)b * 65536;
  const float*  p2rB = P2R + (size_t)b * 65536;

  if (tid < 128) {
    float hbv = h_bar[b * 128 + tid];
    hbar_s[tid] = hbv;
    query[tid] = hbv + vproj[tid];
    qmask[tid] = 0;
  }
  mask[tid] = 0;
  int fc = 0;          // first chosen index (set at t==0; identical across threads)
  float p2l_reg = 0.f; // cached P2L[fc*128+tid] (valid for tid<128 after t==0)
  __syncthreads();

  for (int t = 0; t < 512; t++) {
    float gum = gtb[(size_t)t * 16384 + tid];   // hoisted; completes by phase B

    // A: gq partials  (k = p*32 + 4i + comp, ascending)
    {
      const float4* q4 = (const float4*)query + p * 8;
      const float4* w4 = (const float4*)gq_wT + (size_t)(p * 8) * 128 + j;
      float acc = 0.f;
#pragma unroll
      for (int i = 0; i < 8; i++) {
        float4 x4 = q4[i]; float4 ww = w4[(size_t)i * 128];
        acc += x4.x * ww.x; acc += x4.y * ww.y; acc += x4.z * ww.z; acc += x4.w * ww.w;
      }
      part[p * 128 + j] = acc;
    }
    __syncthreads();
    // B: gqv combine ((p0+p1)+(p2+p3)) + bias
    if (tid < 128)
      gqv[tid] = (part[tid] + part[128 + tid]) + (part[256 + tid] + part[384 + tid]) + gq_b[tid];
    __syncthreads();

    // C: glimpse logits (s = tid), wave max; masked lanes skip loads (dot unused)
    float v[4];
    {
      bool msk = (mask[tid] != 0);
      if (!msk) {
        const float4* q4 = (const float4*)gqv;
#pragma unroll
        for (int hh = 0; hh < 4; hh++) {
          float acc = 0.f;
#pragma unroll
          for (int i = 0; i < 8; i++) {
            float4 qq = q4[hh * 8 + i];
            float4 gg = gk4[(size_t)(hh * 8 + i) * 16384 + tid];
            acc += qq.x * gg.x; acc += qq.y * gg.y; acc += qq.z * gg.z; acc += qq.w * gg.w;
          }
          v[hh] = acc * 0.17677669529663687f;
        }
      } else {
        v[0] = v[1] = v[2] = v[3] = NEGV;
      }
#pragma unroll
      for (int hh = 0; hh < 4; hh++) {
        float x = v[hh];
        for (int off = 32; off; off >>= 1) x = fmaxf(x, __shfl_xor(x, off));
        if (lane == 0) redf[wave * 4 + hh] = x;
      }
    }
    __syncthreads();
    // D: combine max, exp, wave sums
    float e[4];
    {
#pragma unroll
      for (int hh = 0; hh < 4; hh++) {
        float x = redf[hh];
        for (int w = 1; w < 8; w++) x = fmaxf(x, redf[w * 4 + hh]);
        e[hh] = expf(v[hh] - x);
        float sx = e[hh];
        for (int off = 32; off; off >>= 1) sx += __shfl_xor(sx, off);
        if (lane == 0) redf2[wave * 4 + hh] = sx;
      }
    }
    __syncthreads();
    // E: combine sums, write alpha
    {
#pragma unroll
      for (int hh = 0; hh < 4; hh++) {
        float x = 0.f;
        for (int w = 0; w < 8; w++) x += redf2[w * 4 + hh];
        gl[hh * 512 + tid] = e[hh] / x;
      }
    }
    __syncthreads();

    // F: nq partials (i ascending within p), skip fully-masked quads (alpha==+0)
    {
      int hh = j >> 5;
      const float4* al4 = (const float4*)(gl + hh * 512 + p * 128);
      const float4* gp  = gv4b + (size_t)(p * 32) * 128 + j;
      const int* qm = qmask + p * 32;
      float acc = 0.f;
#pragma unroll 4
      for (int i = 0; i < 32; i++) {
        if (!qm[i]) {
          float4 aa = al4[i]; float4 vv = gp[(size_t)i * 128];
          acc += aa.x * vv.x; acc += aa.y * vv.y; acc += aa.z * vv.z; acc += aa.w * vv.w;
        }
      }
      part[p * 128 + j] = acc;
    }
    __syncthreads();
    // G: nq combine (no bias)
    if (tid < 128)
      nq[tid] = (part[tid] + part[128 + tid]) + (part[256 + tid] + part[384 + tid]);
    __syncthreads();

    // H: go partials
    {
      const float4* q4 = (const float4*)nq + p * 8;
      const float4* w4 = (const float4*)go_wT + (size_t)(p * 8) * 128 + j;
      float acc = 0.f;
#pragma unroll
      for (int i = 0; i < 8; i++) {
        float4 x4 = q4[i]; float4 ww = w4[(size_t)i * 128];
        acc += x4.x * ww.x; acc += x4.y * ww.y; acc += x4.z * ww.z; acc += x4.w * ww.w;
      }
      part[p * 128 + j] = acc;
    }
    __syncthreads();
    // I: nq2 combine
    if (tid < 128)
      nq2[tid] = (part[tid] + part[128 + tid]) + (part[256 + tid] + part[384 + tid]) + go_b[tid];
    __syncthreads();

    // J: pq partials
    {
      const float4* q4 = (const float4*)nq2 + p * 8;
      const float4* w4 = (const float4*)pq_wT + (size_t)(p * 8) * 128 + j;
      float acc = 0.f;
#pragma unroll
      for (int i = 0; i < 8; i++) {
        float4 x4 = q4[i]; float4 ww = w4[(size_t)i * 128];
        acc += x4.x * ww.x; acc += x4.y * ww.y; acc += x4.z * ww.z; acc += x4.w * ww.w;
      }
      part[p * 128 + j] = acc;
    }
    __syncthreads();
    // K: pqv combine
    if (tid < 128)
      pqv[tid] = (part[tid] + part[128 + tid]) + (part[256 + tid] + part[384 + tid]) + pq_b[tid];
    __syncthreads();

    // L: pointer logits (s = tid) + gumbel; masked lanes skip loads+tanh
    {
      bool msk = (mask[tid] != 0);
      float plv;
      if (!msk) {
        const float4* q4 = (const float4*)pqv;
        float acc = 0.f;
#pragma unroll 8
        for (int i = 0; i < 32; i++) {
          float4 qq = q4[i];
          float4 pp = pk4[(size_t)i * 16384 + tid];
          acc += qq.x * pp.x; acc += qq.y * pp.y; acc += qq.z * pp.z; acc += qq.w * pp.w;
        }
        plv = 10.0f * tanhf(acc * 0.08838834764831843f);
      } else {
        plv = NEGV;
      }
      pl[tid] = plv;
      float pgv = plv + gum;
      float av = pgv; int ix = tid;
      float mp = plv;
      for (int off = 32; off; off >>= 1) {
        float ov = __shfl_xor(av, off); int oi = __shfl_xor(ix, off);
        if (ov > av || (ov == av && oi < ix)) { av = ov; ix = oi; }
        mp = fmaxf(mp, __shfl_xor(mp, off));
      }
      float ee = expf(plv - mp);
      for (int off = 32; off; off >>= 1) ee += __shfl_xor(ee, off);
      if (lane == 0) { redv[wave] = av; redi[wave] = ix; redm2[wave] = mp; reds2[wave] = ee; }
    }
    __syncthreads();

    // M (merged with O'): combine argmax (all threads, deterministic);
    // outputs + mask/qmask (tid0); query update for next step (tid<128).
    {
      float av = redv[0]; int c = redi[0];
#pragma unroll
      for (int w = 1; w < 8; w++) {
        if (redv[w] > av || (redv[w] == av && redi[w] < c)) { av = redv[w]; c = redi[w]; }
      }
      if (t == 0) fc = c;
      if (tid == 0) {
        float M = redm2[0];
        for (int w = 1; w < 8; w++) M = fmaxf(M, redm2[w]);
        float S = 0.f;
        for (int w = 0; w < 8; w++) S += reds2[w] * expf(redm2[w] - M);
        out[b * 512 + t] = pl[c] - M - logf(S);
        out[16384 + b * 512 + t] = (float)c;
        mask[c] = 1;
        int q = c >> 2;
        qmask[q] = mask[q * 4] & mask[q * 4 + 1] & mask[q * 4 + 2] & mask[q * 4 + 3];
      }
      if (tid < 128) {
        if (t == 0) p2l_reg = p2lB[(size_t)fc * 128 + tid];   // same value every step
        float p2 = p2l_reg + p2rB[(size_t)c * 128 + tid];
        query[tid] = hbar_s[tid] + (p2 + vw_b[tid]);
      }
    }
    __syncthreads();
  }
}

// ---------------- launch ----------------
extern "C" void kernel_launch(void* const* d_in, const int* in_sizes, int n_in,
                              void* d_out, int out_size, void* d_ws, size_t ws_size,
                              hipStream_t stream) {
  (void)in_sizes; (void)n_in; (void)out_size; (void)ws_size;
  const float* inputs     = (const float*)d_in[0];
  const float* emb_w      = (const float*)d_in[1];
  const float* emb_b      = (const float*)d_in[2];
  const float* in_proj_w  = (const float*)d_in[3];
  const float* in_proj_b  = (const float*)d_in[4];
  const float* out_proj_w = (const float*)d_in[5];
  const float* out_proj_b = (const float*)d_in[6];
  const float* ff1_w      = (const float*)d_in[7];
  const float* ff1_b      = (const float*)d_in[8];
  const float* ff2_w      = (const float*)d_in[9];
  const float* ff2_b      = (const float*)d_in[10];
  const float* hctx_w     = (const float*)d_in[11];
  const float* hctx_b     = (const float*)d_in[12];
  const float* vw_w       = (const float*)d_in[13];
  const float* vw_b       = (const float*)d_in[14];
  const float* init_w     = (const float*)d_in[15];
  const float* gq_w = (const float*)d_in[16]; const float* gq_b = (const float*)d_in[17];
  const float* gk_w = (const float*)d_in[18]; const float* gk_b = (const float*)d_in[19];
  const float* gv_w = (const float*)d_in[20]; const float* gv_b = (const float*)d_in[21];
  const float* go_w = (const float*)d_in[22]; const float* go_b = (const float*)d_in[23];
  const float* pq_w = (const float*)d_in[24]; const float* pq_b = (const float*)d_in[25];
  const float* pk_w = (const float*)d_in[26]; const float* pk_b = (const float*)d_in[27];
  float* out = (float*)d_out;

  float* ws   = (float*)d_ws;
  float* h    = ws;                       // 2,097,152
  float* s1   = h + 2097152;              // 8,388,608 encoder scratch
  float* s2   = s1 + 8388608;             // 2,097,152 (attn out; later gkT4)
  float* hbar = s2 + 2097152;             // 4096
  float* vpj  = hbar + 4096;              // 128
  float* wqT  = vpj + 128;                // 16384
  float* woT  = wqT + 16384;              // 16384
  float* wpT  = woT + 16384;              // 16384
  float* vwL  = wpT + 16384;              // 16384
  float* vwR  = vwL + 16384;              // 16384
  float* zeros= vwR + 16384;              // 128
  float* gtab = zeros + 128;              // 8,388,608
  // decode-time overlays of s1 (dead after encoder):
  float* P2Lb = s1;                       // 2,097,152
  float* gv4  = s1 + 2097152;             // 2,097,152
  float* pkT4 = s1 + 4194304;             // 2,097,152
  float* P2Rb = s1 + 6291456;             // 2,097,152
  float* gkT4 = s2;                       // 2,097,152

  const int attn_lds = ATTN_LDS_FLOATS * 4;
  hipFuncSetAttribute((const void*)attn_kernel,
                      hipFuncAttributeMaxDynamicSharedMemorySize, attn_lds);

  gumbel_kernel<<<32768, 256, 0, stream>>>(gtab);
  embed_kernel<<<8192, 256, 0, stream>>>(inputs, emb_w, emb_b, h);
  for (int l = 0; l < 2; l++) {
    gemm_kernel<0><<<dim3(6, 256), 256, 0, stream>>>(
        h, in_proj_w + (size_t)l * 384 * 128, in_proj_b + l * 384, nullptr, s1, 384, 128);
    attn_kernel<<<256, 256, attn_lds, stream>>>(s1, s2);
    gemm_kernel<2><<<dim3(2, 256), 256, 0, stream>>>(
        s2, out_proj_w + (size_t)l * 128 * 128, out_proj_b + l * 128, h, h, 128, 128);
    gemm_kernel<1><<<dim3(8, 256), 256, 0, stream>>>(
        h, ff1_w + (size_t)l * 512 * 128, ff1_b + l * 512, nullptr, s1, 512, 128);
    gemm_kernel<2><<<dim3(2, 256), 256, 0, stream>>>(
        s1, ff2_w + (size_t)l * 128 * 512, ff2_b + l * 128, h, h, 128, 512);
  }
  // decode operand prep (identical layouts to R13/R15)
  hipMemsetAsync(zeros, 0, 512, stream);
  gemm_kernel<3><<<dim3(2, 256), 256, 0, stream>>>(h, gk_w, gk_b, nullptr, gkT4, 128, 128);
  gemm_kernel<4><<<dim3(2, 256), 256, 0, stream>>>(h, gv_w, gv_b, nullptr, gv4, 128, 128);
  gemm_kernel<3><<<dim3(2, 256), 256, 0, stream>>>(h, pk_w, pk_b, nullptr, pkT4, 128, 128);
  wtr4_kernel<<<64, 256, 0, stream>>>(gq_w, wqT, 128, 128);
  wtr4_kernel<<<64, 256, 0, stream>>>(go_w, woT, 128, 128);
  wtr4_kernel<<<64, 256, 0, stream>>>(pq_w, wpT, 128, 128);
  wsplit_kernel<<<64, 256, 0, stream>>>(vw_w, vwL, vwR);
  gemm_kernel<0><<<dim3(2, 256), 256, 0, stream>>>(h, vwL, zeros, nullptr, P2Lb, 128, 128);
  gemm_kernel<0><<<dim3(2, 256), 256, 0, stream>>>(h, vwR, zeros, nullptr, P2Rb, 128, 128);
  hbar_kernel<<<32, 128, 0, stream>>>(h, hctx_w, hctx_b, hbar);
  vproj_kernel<<<1, 128, 0, stream>>>(init_w, vw_w, vw_b, vpj);
  decode_kernel<<<32, 512, 0, stream>>>(gv4, gkT4, pkT4, hbar, vpj,
      wqT, gq_b, woT, go_b, wpT, pq_b, vw_b, gtab, P2Lb, P2Rb, out);
}